// Round 6
// baseline (227.819 us; speedup 1.0000x reference)
//
#include <hip/hip_runtime.h>
#include <float.h>
#include <math.h>

// VQ nearest-codebook: z_e (64,256,32,32) fp32 NCHW, codebook (512,256) fp32.
// token t = n*1024 + hw; feature d at z_e[n*262144 + d*1024 + hw].
// d_out: [0,65536) = q as float; [65536,...) = z_q fp32 NCHW.
//
// Ref model (proven): dists quantized by fp32 expansion with xsq~256;
// scan approximates m = x.w - 0.5|w|^2 (bf16-split MFMA, err ~2.5e-7),
// top-4 per token; if m-gap > MARGIN the argmax is final; else replicate the
// np fp32 quantized distance (xsq_np pairwise, fp64 dot -> fp32) tie->low k.
//
// Round-6 changes (diagnosis: overlap-limited; pipes need MFMA 21 / VALU 31 /
// HBM 21 us but dur=103 at 2 blocks/CU, 39% occupancy):
//  * TPB 64->32: x-LDS 32KB, total ~35KB -> 4 blocks/CU = 8 waves/SIMD
//    (VGPR already exactly 64 = the 32-waves/CU breakpoint; bounds (512,8)).
//  * vq_wsq_np fused into vq_wpack (blocks 0..31 dual-duty, identical bits).

#define KCODES 512
#define DDIM   256
#define HWSZ   1024
#define TTOK   65536
#define TPB    32             // tokens per block
#define NBLK   (TTOK / TPB)   // 2048
#define NCHUNK 16             // k-chunks of 16 dims
#define MARGIN 2.5e-4f

// LDS map (bytes): [0, 33280) reuse region:
//   phase A: x fragments [p:2][c:16][lane:64][16B] = 32768
//   phase B: candm (4KB) @0, candi (4KB) @4096, worklist @8192..9360
//   phase C: z_q row stage, 32 rows x 260 floats (1040B pitch) = 33280
// [33280, 35328): 0.5*wsq (512 floats)
// [35328, 35456): bkArr (32 ints)
#define HW_OFF 33280
#define BK_OFF 35328
#define LDS_SZ 35456
#define ZQ_PITCH 1040         // bytes per staged row (260 floats, 16B aligned)

typedef short bf16x8 __attribute__((ext_vector_type(8)));   // 8 bf16 (4 VGPRs)
typedef float f32x16 __attribute__((ext_vector_type(16)));
typedef float f32x4  __attribute__((ext_vector_type(4)));

__device__ inline unsigned short bf16rne(float x) {
    union { float f; unsigned u; } a; a.f = x;
    unsigned r = a.u + (0x7fffu + ((a.u >> 16) & 1u));
    return (unsigned short)(r >> 16);
}
__device__ inline float bf16tof(unsigned short h) {
    union { unsigned u; float f; } b; b.u = ((unsigned)h) << 16; return b.f;
}

// branchless sorted-descending top-4 insert, strict > (ties keep incumbent)
__device__ __forceinline__ void top4_insert(float m, int c, float fb[4], int fi[4]) {
    #pragma unroll
    for (int l = 0; l < 4; ++l) {
        const bool s = m > fb[l];
        const float nm = s ? fb[l] : m;
        const int   nc = s ? fi[l] : c;
        fb[l] = s ? m : fb[l];
        fi[l] = s ? c : fi[l];
        m = nm; c = nc;
    }
}

// ---------------------------------------------- fused w pack + wsq (np) ----
// ws_w layout: [chunk c:16][part p:2][tile:16][lane:64][16B]  (512 KiB)
// element: code = tile*32 + (lane&31), d = c*16 + (lane>>5)*8 + j
// Blocks 0..31 additionally compute wsq (16 codes each, 16 lanes/code,
// exact np pairwise order: stripe fold + shfl butterfly — bit-identical
// to the previous standalone vq_wsq_np).
__global__ __launch_bounds__(256) void vq_prep(const float* __restrict__ cb,
                                               unsigned char* __restrict__ wsw,
                                               float* __restrict__ wsq) {
    const int tid = threadIdx.x;
    const int gid = blockIdx.x * 256 + tid;           // 16384 total
    {
        const int k = gid >> 5, o = gid & 31;
        const int d0 = o * 8, c = o >> 1, half = o & 1;
        unsigned hi[4], lo[4];
        #pragma unroll
        for (int jj = 0; jj < 4; ++jj) {
            float v0 = cb[k * DDIM + d0 + 2 * jj];
            float v1 = cb[k * DDIM + d0 + 2 * jj + 1];
            unsigned short h0 = bf16rne(v0), h1 = bf16rne(v1);
            unsigned short l0 = bf16rne(v0 - bf16tof(h0));
            unsigned short l1 = bf16rne(v1 - bf16tof(h1));
            hi[jj] = (unsigned)h0 | ((unsigned)h1 << 16);
            lo[jj] = (unsigned)l0 | ((unsigned)l1 << 16);
        }
        const int tile = k >> 5, lane2 = (k & 31) + 32 * half;
        *(uint4*)(wsw + ((size_t)((c * 2 + 0) * 16 + tile) * 1024) + lane2 * 16) = make_uint4(hi[0], hi[1], hi[2], hi[3]);
        *(uint4*)(wsw + ((size_t)((c * 2 + 1) * 16 + tile) * 1024) + lane2 * 16) = make_uint4(lo[0], lo[1], lo[2], lo[3]);
    }
    if (blockIdx.x < 32) {
        const int k = blockIdx.x * 16 + (tid >> 4);
        const int s = tid & 15, h2 = s >> 3, j2 = s & 7;
        const float* p = cb + (size_t)k * DDIM + h2 * 128 + j2;
        float v[16];
        #pragma unroll
        for (int i = 0; i < 16; ++i) v[i] = p[i * 8];
        float rr;
        {
#pragma clang fp contract(off)
            rr = v[0] * v[0];
            #pragma unroll
            for (int i = 1; i < 16; ++i) { float sq = v[i] * v[i]; rr = rr + sq; }
        }
        float t = rr;
        t = t + __shfl_xor(t, 1);
        t = t + __shfl_xor(t, 2);
        t = t + __shfl_xor(t, 4);
        t = t + __shfl_xor(t, 8);
        if (s == 0) wsq[k] = t;
    }
}

// ---------------------------------------------------------------- main -----
// 2048 blocks x 512 threads (8 waves). Block = 32 tokens x 512 codes.
// Wave wv owns code tiles {2wv, 2wv+1} (64 codes) over all 32 tokens.
__global__ __launch_bounds__(512, 8) void vq_main(const float* __restrict__ z_e,
                                                  const float* __restrict__ cb,
                                                  const float* __restrict__ wsq,
                                                  const unsigned char* __restrict__ wsw,
                                                  float* __restrict__ out) {
    __shared__ __align__(16) unsigned char lds[LDS_SZ];

    const int tid = threadIdx.x;
    const int wv = tid >> 6, lane = tid & 63;
    const int tbase = blockIdx.x * TPB;
    const int n = tbase >> 10, hw0 = tbase & (HWSZ - 1);
    const float* zb = z_e + (size_t)n * (DDIM * HWSZ) + hw0;

    // ---- stage x -> LDS (bf16 hi/lo, fragment-packed, b128 writes) ----
    // x layout: [p:2][c:16][lane:64][16B]; 16 threads per token.
    {
        const int tok = tid & 31, g = (tid >> 5) & 15;   // g = chunk
        #pragma unroll
        for (int o = 0; o < 2; ++o) {
            const int d0 = g * 16 + o * 8;
            float v[8];
            #pragma unroll
            for (int j = 0; j < 8; ++j) v[j] = zb[(size_t)(d0 + j) * HWSZ + tok];
            unsigned hi[4], lo[4];
            #pragma unroll
            for (int jj = 0; jj < 4; ++jj) {
                unsigned short h0 = bf16rne(v[2 * jj]), h1 = bf16rne(v[2 * jj + 1]);
                unsigned short l0 = bf16rne(v[2 * jj] - bf16tof(h0));
                unsigned short l1 = bf16rne(v[2 * jj + 1] - bf16tof(h1));
                hi[jj] = (unsigned)h0 | ((unsigned)h1 << 16);
                lo[jj] = (unsigned)l0 | ((unsigned)l1 << 16);
            }
            const int off2 = tok * 16 + 512 * o;
            *(uint4*)(lds + ((0 * 16 + g)) * 1024 + off2) = make_uint4(hi[0], hi[1], hi[2], hi[3]);
            *(uint4*)(lds + ((1 * 16 + g)) * 1024 + off2) = make_uint4(lo[0], lo[1], lo[2], lo[3]);
        }
    }
    // ---- stage 0.5*wsq -> LDS (2KB, broadcast-read in the fold) ----
    ((float*)(lds + HW_OFF))[tid] = 0.5f * wsq[tid];

    __syncthreads();

    // ---- K-loop: 1 pair of 32-code tiles/wave, reg-double-buffered ----
    const int hh = lane >> 5;           // which 16-row half of each 32-code tile
    const int ct0 = wv * 2;             // this wave's code tiles
    const float* hwsqL = (const float*)(lds + HW_OFF);

    #define LDW(c, p, t)   (*(const bf16x8*)(wsw + ((size_t)(((c) * 2 + (p)) * 16 + (t)) * 1024) + lane * 16))
    #define LDA(p, c)      (*(const bf16x8*)(lds + (((p) * 16 + (c))) * 1024 + lane * 16))

    float fb[4] = {-FLT_MAX, -FLT_MAX, -FLT_MAX, -FLT_MAX};
    int   fi[4] = {KCODES, KCODES, KCODES, KCODES};

    {
        f32x16 a0, a1;
        #pragma unroll
        for (int r = 0; r < 16; ++r) { a0[r] = 0.f; a1[r] = 0.f; }
        bf16x8 Xc[2][2], Wc[2][4];
        Xc[0][0] = LDA(0, 0);  Xc[0][1] = LDA(1, 0);
        Wc[0][0] = LDW(0, 0, ct0); Wc[0][1] = LDW(0, 1, ct0);
        Wc[0][2] = LDW(0, 0, ct0 + 1); Wc[0][3] = LDW(0, 1, ct0 + 1);
        #pragma unroll
        for (int c = 0; c < NCHUNK; ++c) {
            const int cur = c & 1, nxt = cur ^ 1;
            if (c + 1 < NCHUNK) {
                Xc[nxt][0] = LDA(0, c + 1);  Xc[nxt][1] = LDA(1, c + 1);
                Wc[nxt][0] = LDW(c + 1, 0, ct0); Wc[nxt][1] = LDW(c + 1, 1, ct0);
                Wc[nxt][2] = LDW(c + 1, 0, ct0 + 1); Wc[nxt][3] = LDW(c + 1, 1, ct0 + 1);
            }
            // m = xh*wh + xh*wl + xl*wh  (A=w / B=x)
            a0 = __builtin_amdgcn_mfma_f32_32x32x16_bf16(Wc[cur][0], Xc[cur][0], a0, 0, 0, 0);
            a1 = __builtin_amdgcn_mfma_f32_32x32x16_bf16(Wc[cur][2], Xc[cur][0], a1, 0, 0, 0);
            a0 = __builtin_amdgcn_mfma_f32_32x32x16_bf16(Wc[cur][1], Xc[cur][0], a0, 0, 0, 0);
            a1 = __builtin_amdgcn_mfma_f32_32x32x16_bf16(Wc[cur][3], Xc[cur][0], a1, 0, 0, 0);
            a0 = __builtin_amdgcn_mfma_f32_32x32x16_bf16(Wc[cur][0], Xc[cur][1], a0, 0, 0, 0);
            a1 = __builtin_amdgcn_mfma_f32_32x32x16_bf16(Wc[cur][2], Xc[cur][1], a1, 0, 0, 0);
        }
        // C layout (32x32x16): col = lane&31 = token, row = (reg&3)+8*(reg>>2)+4*hh = code%32
        #pragma unroll
        for (int rq = 0; rq < 4; ++rq) {
            const f32x4 h40 = *(const f32x4*)(hwsqL + ct0 * 32 + rq * 8 + 4 * hh);
            const f32x4 h41 = *(const f32x4*)(hwsqL + (ct0 + 1) * 32 + rq * 8 + 4 * hh);
            #pragma unroll
            for (int rr = 0; rr < 4; ++rr) {
                top4_insert(a0[rq * 4 + rr] - h40[rr], ct0 * 32 + rr + 8 * rq + 4 * hh, fb, fi);
                top4_insert(a1[rq * 4 + rr] - h41[rr], (ct0 + 1) * 32 + rr + 8 * rq + 4 * hh, fb, fi);
            }
        }
    }

    // ---- pair merge: lane <-> lane^32 (two 16-row halves of same token) ----
    {
        float sb[4]; int si[4];
        #pragma unroll
        for (int c = 0; c < 4; ++c) { sb[c] = __shfl_xor(fb[c], 32); si[c] = __shfl_xor(fi[c], 32); }
        #pragma unroll
        for (int c = 0; c < 4; ++c) top4_insert(sb[c], si[c], fb, fi);
    }

    // ---- publish per-wave top-4, merge across waves ----
    __syncthreads();                    // all LDS x reads done; reuse region
    float* candm = (float*)lds;                 // 1024 floats
    int*   candi = (int*)(lds + 4096);          // 1024 ints
    int*   wlCnt = (int*)(lds + 8192);
    int*   wlTok = (int*)(lds + 8208);          // 32 ints
    int*   wlGi  = (int*)(lds + 8336);          // 32*4 ints
    float* wlG   = (float*)(lds + 8848);        // 32*4 floats
    int*   bkArr = (int*)(lds + BK_OFF);        // 32 ints
    if (lane < 32) {
        const int slot = (wv * 32 + lane) * 4;
        #pragma unroll
        for (int c = 0; c < 4; ++c) { candm[slot + c] = fb[c]; candi[slot + c] = fi[c]; }
    }
    if (tid == 0) *wlCnt = 0;
    __syncthreads();

    if (tid < TPB) {
        float g[4] = {-FLT_MAX, -FLT_MAX, -FLT_MAX, -FLT_MAX};
        int  gi[4] = {KCODES, KCODES, KCODES, KCODES};
        #pragma unroll
        for (int w8 = 0; w8 < 8; ++w8) {
            const int slot = (w8 * 32 + tid) * 4;
            #pragma unroll
            for (int c = 0; c < 4; ++c) top4_insert(candm[slot + c], candi[slot + c], g, gi);
        }
        if (g[0] - g[1] > MARGIN) {
            // gap >> quantization window: argmax final, no tie possible
            out[tbase + tid] = (float)gi[0];
            bkArr[tid] = gi[0];
        } else {
            const int slot = atomicAdd(wlCnt, 1);
            wlTok[slot] = tid;
            #pragma unroll
            for (int c = 0; c < 4; ++c) { wlGi[slot * 4 + c] = gi[c]; wlG[slot * 4 + c] = g[c]; }
        }
    }
    __syncthreads();

    // ---- adjudication: all 8 waves round-robin the worklist; one wave/item ----
    {
        const int nIt = *wlCnt;
        for (int it = wv; it < nIt; it += 8) {
            const int tok = wlTok[it];
            const float g0 = wlG[it * 4];
            const float* xa = zb + tok;

            // xsq: bitwise np pairwise. Lane s<16 (s = h*8+j) runs stripe j of
            // half h as a serial 16-term fold; butterfly reproduces the exact
            // pairwise combine ((r0+r1)+(r2+r3))+((r4+r5)+(r6+r7)), sh0+sh1.
            float xsq;
            {
                const int h2 = (lane >> 3) & 1, j2 = lane & 7;
                float v[16];
                if (lane < 16) {
                    #pragma unroll
                    for (int i = 0; i < 16; ++i)
                        v[i] = xa[(size_t)(h2 * 128 + i * 8 + j2) * HWSZ];
                } else {
                    #pragma unroll
                    for (int i = 0; i < 16; ++i) v[i] = 0.f;
                }
                float rr;
                {
#pragma clang fp contract(off)
                    rr = v[0] * v[0];
                    #pragma unroll
                    for (int i = 1; i < 16; ++i) { float sq = v[i] * v[i]; rr = rr + sq; }
                }
                float t = rr;
                t = t + __shfl_xor(t, 1);
                t = t + __shfl_xor(t, 2);
                t = t + __shfl_xor(t, 4);
                t = t + __shfl_xor(t, 8);
                xsq = __shfl(t, 0);
            }

            // x column into regs for the dots (lane d0 = lane, +64 strides)
            double xv[4];
            #pragma unroll
            for (int i = 0; i < 4; ++i)
                xv[i] = (double)xa[(size_t)(lane + 64 * i) * HWSZ];

            float bestd = FLT_MAX; int bestk = KCODES;
            #pragma unroll
            for (int c = 0; c < 4; ++c) {
                const float gc = wlG[it * 4 + c];
                if (c > 0 && g0 - gc > MARGIN) break;   // wave-uniform
                const int idx = wlGi[it * 4 + c];
                const float* wr = cb + (size_t)idx * DDIM;
                double A = 0.0;
                #pragma unroll
                for (int i = 0; i < 4; ++i)
                    A = fma((double)wr[lane + 64 * i], xv[i], A);
                // fp64 butterfly reduce (order-free: 29 spare bits vs fp32)
                A = A + __shfl_xor(A, 1);
                A = A + __shfl_xor(A, 2);
                A = A + __shfl_xor(A, 4);
                A = A + __shfl_xor(A, 8);
                A = A + __shfl_xor(A, 16);
                A = A + __shfl_xor(A, 32);
                float dist;
                {
#pragma clang fp contract(off)
                    const float xw = (float)A;
                    const float t1 = xsq - 2.0f * xw;
                    dist = t1 + wsq[idx];
                }
                if (dist < bestd || (dist == bestd && idx < bestk)) { bestd = dist; bestk = idx; }
            }
            if (lane == 0) {
                out[tbase + tok] = (float)bestk;
                bkArr[tok] = bestk;
            }
        }
    }
    __syncthreads();

    // ---- z_q: stage selected rows into LDS (coalesced row reads) ----
    {
        #pragma unroll
        for (int rr = 0; rr < 4; ++rr) {
            const int r = wv * 4 + rr;
            const int bk = bkArr[r];                              // wave-uniform
            const float4 vv = *(const float4*)(cb + (size_t)bk * DDIM + lane * 4);
            *(float4*)(lds + r * ZQ_PITCH + lane * 16) = vv;
        }
    }
    __syncthreads();

    // ---- z_q write (coalesced over tokens, sourced from LDS) ----
    {
        const int tk = tid & 31, s = tid >> 5;     // s = 0..15, 16 dims each
        float* zq = out + TTOK + (size_t)n * (DDIM * HWSZ) + hw0 + tk;
        #pragma unroll
        for (int i = 0; i < 16; i += 4) {
            const f32x4 v = *(const f32x4*)(lds + tk * ZQ_PITCH + (s * 16 + i) * 4);
            #pragma unroll
            for (int j = 0; j < 4; ++j)
                zq[(size_t)(s * 16 + i + j) * HWSZ] = v[j];
        }
    }
}

// --------------------------------------------------------------- launch ----
extern "C" void kernel_launch(void* const* d_in, const int* in_sizes, int n_in,
                              void* d_out, int out_size, void* d_ws, size_t ws_size,
                              hipStream_t stream) {
    const float* z_e = (const float*)d_in[0];
    const float* cb  = (const float*)d_in[1];
    float* out = (float*)d_out;
    float* wsq = (float*)d_ws;                              // 2 KiB
    unsigned char* wsw = (unsigned char*)d_ws + 2048;       // 512 KiB fragment-packed w

    vq_prep<<<64, 256, 0, stream>>>(cb, wsw, wsq);
    vq_main<<<NBLK, 512, 0, stream>>>(z_e, cb, wsq, wsw, out);
}